// Round 6
// baseline (194.714 us; speedup 1.0000x reference)
//
#include <hip/hip_runtime.h>
#include <hip/hip_bf16.h>

#define N_NODES 10000
#define KP      10240   // K padded; xwt pad region is ZERO
#define F       128
#define BK      64      // K-tile
#define NT      160     // KP / BK

typedef float  f32x4  __attribute__((ext_vector_type(4)));
typedef short  bf16x8 __attribute__((ext_vector_type(8)));
typedef short  s16x8  __attribute__((ext_vector_type(8)));
typedef short  s16x4  __attribute__((ext_vector_type(4)));
typedef unsigned int u32x4 __attribute__((ext_vector_type(4)));

// f32 -> bf16 round-to-nearest-even (finite inputs only)
static __device__ __forceinline__ unsigned short f2bf(float f) {
    unsigned u = __builtin_bit_cast(unsigned, f);
    u += 0x7FFFu + ((u >> 16) & 1u);
    return (unsigned short)(u >> 16);
}

static __device__ __forceinline__ s16x4 pack4(f32x4 v) {
    s16x4 r;
    r[0] = (short)f2bf(v[0]); r[1] = (short)f2bf(v[1]);
    r[2] = (short)f2bf(v[2]); r[3] = (short)f2bf(v[3]);
    return r;
}

// ---------------------------------------------------------------------------
// Kernel 1: xwt = (X @ W1)^T bf16 in MFMA-native tiles:
//   [kc(320)][ct(8)][c(16)][k32] ; 16B unit u (in-tile) = kc2*512+ct*64+c*4+ku
// grid 640 x 256; pad k (nodes >= 10000) -> 0.
// ---------------------------------------------------------------------------
__global__ __launch_bounds__(256) void k_xw(const float* __restrict__ x,
                                            const float* __restrict__ W1,
                                            unsigned short* __restrict__ xwt) {
    __shared__ float xs[16][128];              // 8 KB
    __shared__ unsigned short ts[16][136];     // [node][col] staging (padded)
    const int t  = threadIdx.x;
    const int nb = blockIdx.x * 16;

    #pragma unroll
    for (int i = 0; i < 2; ++i) {
        int idx = t + i * 256;         // float4 index, 512 total
        int n   = idx >> 5;            // 32 float4 per row
        int c4  = idx & 31;
        int gn  = nb + n; if (gn > N_NODES - 1) gn = N_NODES - 1;
        f32x4 v = *reinterpret_cast<const f32x4*>(x + (size_t)gn * F + c4 * 4);
        *reinterpret_cast<f32x4*>(&xs[n][c4 * 4]) = v;
    }
    __syncthreads();

    const int f  = t & 127;
    const int ng = t >> 7;             // 0..1 -> nodes ng*8..+8
    float acc[8] = {0.f, 0.f, 0.f, 0.f, 0.f, 0.f, 0.f, 0.f};

    for (int c4 = 0; c4 < 32; ++c4) {
        float w0 = W1[(4 * c4 + 0) * F + f];
        float w1 = W1[(4 * c4 + 1) * F + f];
        float w2 = W1[(4 * c4 + 2) * F + f];
        float w3 = W1[(4 * c4 + 3) * F + f];
        #pragma unroll
        for (int i = 0; i < 8; ++i) {
            f32x4 xv = *reinterpret_cast<const f32x4*>(&xs[ng * 8 + i][c4 * 4]);
            acc[i] = fmaf(xv.x, w0, fmaf(xv.y, w1, fmaf(xv.z, w2, fmaf(xv.w, w3, acc[i]))));
        }
    }

    #pragma unroll
    for (int i = 0; i < 8; ++i) ts[ng * 8 + i][f] = f2bf(acc[i]);
    __syncthreads();

    {
        const int col = t >> 1, half = t & 1;
        s16x8 v8;
        #pragma unroll
        for (int i = 0; i < 8; ++i) {
            int n = half * 8 + i;
            v8[i] = (nb + n < N_NODES) ? (short)ts[n][col] : (short)0;
        }
        const int kc = nb >> 5, khalf = (nb >> 4) & 1;
        size_t off = (size_t)kc * 4096 + (size_t)(col >> 4) * 512
                   + (size_t)(col & 15) * 32 + khalf * 16 + half * 8;
        *reinterpret_cast<s16x8*>(xwt + off) = v8;
    }
}

// ---------------------------------------------------------------------------
// Kernel 2: out = relu(A @ XW + b1) @ W2 + b2, fused.
// grid 625 x 256; 16 rows/block; BK=64. Waves: ks = w>>1 (k-half),
// ch = w&1 (col-half); per tile per wave: 1 A ds_read + 4 B ds_read + 4 MFMA.
// Raw s_barrier + lgkmcnt(0) only (prefetch loads stay in flight -> counted
// vmcnt by compiler). Dual named staging reg sets, depth-2 pipeline.
// ---------------------------------------------------------------------------
#define SYNC() do { asm volatile("s_waitcnt lgkmcnt(0)" ::: "memory"); \
                    __builtin_amdgcn_s_barrier(); } while (0)

#define LOADT(tile, ra, rb) do {                                                  \
    size_t _ao = arow + (size_t)(tile) * BK; if (_ao > alim) _ao = alim;          \
    ra = __builtin_nontemporal_load(reinterpret_cast<const f32x4*>(A + _ao));     \
    const u32x4* _bs = reinterpret_cast<const u32x4*>(xwt) + (size_t)(tile) * 1024 + t; \
    _Pragma("unroll")                                                             \
    for (int _i = 0; _i < 4; ++_i) rb[_i] = _bs[_i * 256];                        \
} while (0)

#define WRT(bufA, bufB, ra, rb) do {                                              \
    *reinterpret_cast<s16x4*>((bufA) + a_dst) = pack4(ra);                        \
    u32x4* _bd = reinterpret_cast<u32x4*>(bufB);                                  \
    _Pragma("unroll")                                                             \
    for (int _i = 0; _i < 4; ++_i) _bd[b_dst[_i]] = rb[_i];                       \
} while (0)

#define COMPUTE(bufA, bufB) do {                                                  \
    bf16x8 _af = *reinterpret_cast<const bf16x8*>((bufA) + a_src);                \
    const unsigned char* _bb = (bufB) + b_src;                                    \
    bf16x8 _b0 = *reinterpret_cast<const bf16x8*>(_bb);                           \
    bf16x8 _b1 = *reinterpret_cast<const bf16x8*>(_bb + 1024);                    \
    bf16x8 _b2 = *reinterpret_cast<const bf16x8*>(_bb + 2048);                    \
    bf16x8 _b3 = *reinterpret_cast<const bf16x8*>(_bb + 3072);                    \
    acc0 = __builtin_amdgcn_mfma_f32_16x16x32_bf16(_af, _b0, acc0, 0, 0, 0);      \
    acc1 = __builtin_amdgcn_mfma_f32_16x16x32_bf16(_af, _b1, acc1, 0, 0, 0);      \
    acc2 = __builtin_amdgcn_mfma_f32_16x16x32_bf16(_af, _b2, acc2, 0, 0, 0);      \
    acc3 = __builtin_amdgcn_mfma_f32_16x16x32_bf16(_af, _b3, acc3, 0, 0, 0);      \
} while (0)

__global__ __launch_bounds__(256, 4) void k_gcn(const float* __restrict__ A,
                                                const unsigned short* __restrict__ xwt,
                                                const float* __restrict__ b1,
                                                const float* __restrict__ W2,
                                                const float* __restrict__ b2,
                                                float* __restrict__ out) {
    __shared__ __align__(16) unsigned char smem[36864];
    unsigned char* const Bs0 = smem;             // 16 KB
    unsigned char* const Bs1 = smem + 16384;     // 16 KB
    unsigned char* const As0 = smem + 32768;     // 2 KB
    unsigned char* const As1 = smem + 34816;     // 2 KB
    float (*red)[16][132] = reinterpret_cast<float (*)[16][132]>(smem); // overlay

    const int t    = threadIdx.x;
    const int wave = t >> 6;
    const int lane = t & 63;
    const int l16  = lane & 15;
    const int g    = lane >> 4;
    const int ks   = wave >> 1;      // k-half of tile
    const int ch   = wave & 1;       // col-half
    const int rbase = blockIdx.x * 16;   // 10000 = 625*16

    // A staging: thread t -> row t>>4, 4-float chunk q = t&15
    const int sr = t >> 4, q = t & 15;
    const size_t arow = (size_t)(rbase + sr) * N_NODES + q * 4;
    const size_t alim = (size_t)N_NODES * N_NODES - 4;
    const int a_dst = (sr * 8 + ((q >> 1) ^ (sr & 7))) * 16 + (q & 1) * 8;

    // B staging dests: source unit u = t + 256*i (coalesced 1KB/instr);
    // dest = kc2*512 + ch*256 + cc*64 + ku*16 + (c ^ (ku<<2))  [16B units]
    int b_dst[4];
    #pragma unroll
    for (int i = 0; i < 4; ++i) {
        int u  = t + 256 * i;
        int ku = u & 3, c = (u >> 2) & 15, ct = (u >> 6) & 7, kc2 = u >> 9;
        b_dst[i] = kc2 * 512 + (ct >> 2) * 256 + (ct & 3) * 64 + ku * 16 + (c ^ (ku << 2));
    }

    // fragment read byte offsets
    const int a_src = (l16 * 8 + ((ks * 4 + g) ^ (l16 & 7))) * 16;
    const int b_src = (ks * 512 + ch * 256 + g * 16 + (l16 ^ (g << 2))) * 16;

    f32x4 acc0 = {0.f, 0.f, 0.f, 0.f}, acc1 = acc0, acc2 = acc0, acc3 = acc0;

    f32x4 ra_A, ra_B;
    u32x4 rb_A[4], rb_B[4];

    // prologue: 2 tiles in flight
    LOADT(0, ra_A, rb_A);
    LOADT(1, ra_B, rb_B);
    WRT(As0, Bs0, ra_A, rb_A);     // compiler waits only set-A's loads
    SYNC();

    for (int tile = 0; tile < NT; tile += 2) {
        // even: compute buf0, fill buf1 from set B, prefetch tile+2 -> set A
        if (tile + 2 < NT) LOADT(tile + 2, ra_A, rb_A);
        COMPUTE(As0, Bs0);
        WRT(As1, Bs1, ra_B, rb_B);
        SYNC();
        // odd: compute buf1, fill buf0 from set A, prefetch tile+3 -> set B
        if (tile + 3 < NT) LOADT(tile + 3, ra_B, rb_B);
        COMPUTE(As1, Bs1);
        if (tile + 2 < NT) WRT(As0, Bs0, ra_A, rb_A);
        SYNC();
    }

    // epilogue: cross-wave (ks) reduce + bias + relu + dot(W2) + b2
    // C/D layout (m89): col = lane&15, row = (lane>>4)*4 + reg
    #pragma unroll
    for (int e = 0; e < 4; ++e) {
        red[wave][g * 4 + e][ch * 64 +  0 + l16] = acc0[e];
        red[wave][g * 4 + e][ch * 64 + 16 + l16] = acc1[e];
        red[wave][g * 4 + e][ch * 64 + 32 + l16] = acc2[e];
        red[wave][g * 4 + e][ch * 64 + 48 + l16] = acc3[e];
    }
    __syncthreads();

    {
        const int r  = t >> 4;          // 0..15 local row
        const int jj = t & 15;          // 16 threads/row, 8 cols each
        float p = 0.f;
        #pragma unroll
        for (int i = 0; i < 8; ++i) {
            int c  = jj * 8 + i;
            int w0 = c >> 6;            // col-half -> wave pair (w0, w0+2)
            float v = red[w0][r][c] + red[w0 + 2][r][c] + b1[c];
            v = fmaxf(v, 0.f);
            p = fmaf(v, W2[c], p);
        }
        p += __shfl_xor(p, 1);
        p += __shfl_xor(p, 2);
        p += __shfl_xor(p, 4);
        p += __shfl_xor(p, 8);
        if (jj == 0) out[rbase + r] = p + b2[0];
    }
}

extern "C" void kernel_launch(void* const* d_in, const int* in_sizes, int n_in,
                              void* d_out, int out_size, void* d_ws, size_t ws_size,
                              hipStream_t stream) {
    const float* x  = (const float*)d_in[0];
    const float* a  = (const float*)d_in[1];
    const float* W1 = (const float*)d_in[2];
    const float* b1 = (const float*)d_in[3];
    const float* W2 = (const float*)d_in[4];
    const float* b2 = (const float*)d_in[5];
    float* out = (float*)d_out;
    unsigned short* xwt = (unsigned short*)d_ws;   // 320*8KB = 2.62 MB tiled scratch

    k_xw<<<640, 256, 0, stream>>>(x, W1, xwt);     // fills all slabs incl. zero pad
    k_gcn<<<625, 256, 0, stream>>>(a, xwt, b1, W2, b2, out);
}